// Round 3
// baseline (1711.462 us; speedup 1.0000x reference)
//
#include <hip/hip_runtime.h>
#include <stdint.h>

typedef unsigned char u8;
typedef unsigned short u16;
typedef unsigned int u32;
typedef unsigned long long u64;

// ---- problem constants ----
// B=128 S=128 WL=16 V=50000 C=100 T=17 WE=300 CE=50 CF=50 K=3 H=256 D=350
#define NPOS 16384          // B*S
#define KPAD 384            // D padded to multiple of 64

typedef __attribute__((ext_vector_type(8))) short bf16x8;
typedef __attribute__((ext_vector_type(4))) float f32x4;
typedef __attribute__((ext_vector_type(16))) float f32x16;
typedef __attribute__((ext_vector_type(16))) u64 u64x16;

__device__ __forceinline__ float bf2f(u16 u) { return __uint_as_float(((u32)u) << 16); }
__device__ __forceinline__ u16 f2bf(float f) {
    u32 u = __float_as_uint(f);
    u += 0x7fffu + ((u >> 16) & 1u);   // RNE
    return (u16)(u >> 16);
}
__device__ __forceinline__ float sigm(float x) { return 1.0f / (1.0f + __expf(-x)); }
__device__ __forceinline__ float tanh_(float x) { return 2.0f / (1.0f + __expf(-2.0f * x)) - 1.0f; }

// f32 -> fp8 e4m3fn (OCP), RNE, clamp to +-448. Prep-path (manual, no builtin risk).
__device__ u8 f2fp8_manual(float f) {
    u32 u = __float_as_uint(f);
    u32 s = (u >> 31) << 7;
    u32 ae = (u >> 23) & 255u;
    u32 m = u & 0x7fffffu;
    int e = (int)ae - 127;
    if (ae == 0) return (u8)s;                 // f32 subnormal -> 0
    if (e >= 9) return (u8)(s | 0x7e);         // >= 512 -> clamp 448
    if (e >= -6) {                             // e4m3 normal
        u32 mant = m >> 20;
        u32 rem = m & 0xfffffu;
        if (rem > 0x80000u || (rem == 0x80000u && (mant & 1u))) mant++;
        u32 ef = (u32)(e + 7);
        if (mant == 8u) { mant = 0u; ef++; }
        if (ef >= 16u || (ef == 15u && mant == 7u)) return (u8)(s | 0x7e);
        return (u8)(s | (ef << 3) | mant);
    }
    if (e < -10) return (u8)s;                 // underflow to 0
    int sb = 14 - e;                           // shift for units of 2^-9
    u32 X = 0x800000u | m;
    u32 mant = X >> sb;
    u32 rem = X & ((1u << sb) - 1u);
    u32 half = 1u << (sb - 1);
    if (rem > half || (rem == half && (mant & 1u))) mant++;
    if (mant >= 8u) return (u8)(s | (1u << 3)); // rounds to first normal 2^-6
    return (u8)(s | mant);
}

__device__ __forceinline__ u8 f2fp8(float f) {
#if __has_builtin(__builtin_amdgcn_cvt_pk_fp8_f32)
    return (u8)(__builtin_amdgcn_cvt_pk_fp8_f32(f, f, 0, false) & 0xff);
#else
    return f2fp8_manual(f);
#endif
}

// ---- workspace layout (bytes) ----
static constexpr size_t OFF_INP  = 0;                       // u16 [16384][384]   = 12582912
static constexpr size_t OFF_WIH  = 12582912;                // u16 [2048][384]    = 1572864
static constexpr size_t OFF_WHH  = 14155776;                // fp8 packed 512KB
static constexpr size_t OFF_XG   = 15204352;                // u16 xg2 repacked   = 67108864
static constexpr size_t OFF_HS   = 82313216;                // u16 [16384][512]   = 16777216
static constexpr size_t OFF_EMIS = 99090432;                // f32 [16384][17]    = 1114112
static constexpr size_t OFF_NLL  = 100204544;               // f32 [128]

// ============================================================
// Prep: pack [w_ih_f; w_ih_b] into bf16 [2048][384] (K padded w/ zeros)
// ============================================================
__global__ __launch_bounds__(128) void k_prep_wih(const float* __restrict__ wf,
                                                  const float* __restrict__ wb,
                                                  u16* __restrict__ wih) {
    int n = blockIdx.x, tid = threadIdx.x;
    const float* src = (n < 1024) ? (wf + (size_t)n * 350) : (wb + (size_t)(n - 1024) * 350);
    u16* dst = wih + (size_t)n * KPAD;
    for (int k = tid; k < KPAD; k += 128) dst[k] = (k < 350) ? f2bf(src[k]) : (u16)0;
}

// ============================================================
// Prep: w_hh (both dirs) -> fp8, packed for register-resident B-frags:
// whh8[((d*8+hb)*4+g)*8192 + kc*512 + kh*256 + ho*8 + e], k = kc*16+kh*8+e
// ============================================================
__global__ __launch_bounds__(128) void k_prep_whh8(const float* __restrict__ wf,
                                                   const float* __restrict__ wb,
                                                   u8* __restrict__ whh8) {
    int bx = blockIdx.x, tid = threadIdx.x;
    int d = bx >> 10, row = bx & 1023;                 // row = gate*256 + hid
    const float* src = (d ? wb : wf) + (size_t)row * 256;
    int g = row >> 8, hid = row & 255, hb = hid >> 5, ho = hid & 31;
    u8* dst = whh8 + ((size_t)((d * 8 + hb) * 4 + g)) * 8192;
    for (int k = tid; k < 256; k += 128) {
        int kc = k >> 4, kh = (k >> 3) & 1, e = k & 7;
        dst[kc * 512 + kh * 256 + ho * 8 + e] = f2fp8_manual(src[k]);
    }
}

// ============================================================
// Embedding + char conv + concat -> inp bf16 [16384][384]
// ============================================================
__global__ __launch_bounds__(128) void k_embed_conv(const int* __restrict__ words,
                                                    const int* __restrict__ chars,
                                                    const float* __restrict__ word_emb,
                                                    const float* __restrict__ char_emb,
                                                    const float* __restrict__ conv_w,
                                                    const float* __restrict__ conv_b,
                                                    u16* __restrict__ inp) {
    int pos = blockIdx.x, tid = threadIdx.x;
    __shared__ float ce[18 * 50];                      // rows 0 and 17 are zero pad
    const int* ch = chars + (size_t)pos * 16;
    for (int i = tid; i < 18 * 50; i += 128) {
        int row = i / 50, c = i - row * 50;
        float v = 0.f;
        if (row >= 1 && row <= 16) v = char_emb[(size_t)ch[row - 1] * 50 + c];
        ce[i] = v;
    }
    __syncthreads();
    {   // word embedding copy + zero pad
        const float* we = word_emb + (size_t)words[pos] * 300;
        u16* op = inp + (size_t)pos * KPAD;
        for (int c = tid; c < 300; c += 128) op[c] = f2bf(we[c]);
        for (int c = 350 + tid; c < KPAD; c += 128) op[c] = 0;
    }
    if (tid < 100) {
        int oc = tid >> 1, half = tid & 1, t0 = half * 8;
        float acc[8];
#pragma unroll
        for (int tt = 0; tt < 8; ++tt) acc[tt] = 0.f;
        const float* wrow = conv_w + (size_t)oc * 150;
        for (int ic = 0; ic < 50; ++ic) {
#pragma unroll
            for (int k = 0; k < 3; ++k) {
                float wv = wrow[ic * 3 + k];
#pragma unroll
                for (int tt = 0; tt < 8; ++tt)
                    acc[tt] = fmaf(ce[(t0 + tt + k) * 50 + ic], wv, acc[tt]);
            }
        }
        float cb = conv_b[oc];
        float m = 0.f;                                  // relu floor
#pragma unroll
        for (int tt = 0; tt < 8; ++tt) m = fmaxf(m, acc[tt] + cb);
        m = fmaxf(m, __shfl_xor(m, 1));
        if (half == 0) inp[(size_t)pos * KPAD + 300 + oc] = f2bf(m);
    }
}

// ============================================================
// GEMM: inp[16384][384] @ wih[2048][384]^T (bf16 MFMA), epilogue writes xg2:
// xg2 slot = (((((d*4+grp)*128 + tt)*8 + hb)*8 + i)*64 + lane2)*8 + (reg&1)*4 + gate
// with bwd time axis pre-reversed per row (tt), so k_lstm reads linear slabs.
// ============================================================
__global__ __launch_bounds__(256, 2) void k_gemm(const u16* __restrict__ A,
                                                 const u16* __restrict__ Bm,
                                                 u16* __restrict__ C,
                                                 const int* __restrict__ lengths) {
    __shared__ u16 sa[128 * 64];
    __shared__ u16 sb[128 * 64];
    int tid = threadIdx.x;
    int n0 = blockIdx.x * 128, m0 = blockIdx.y * 128;
    int lane = tid & 63, wid = tid >> 6;
    int wr = wid >> 1, wc = wid & 1;
    f32x4 acc[4][4];
#pragma unroll
    for (int mt = 0; mt < 4; ++mt)
#pragma unroll
        for (int nt = 0; nt < 4; ++nt) acc[mt][nt] = (f32x4){0.f, 0.f, 0.f, 0.f};

    for (int kt = 0; kt < 6; ++kt) {
#pragma unroll
        for (int c = 0; c < 4; ++c) {
            int idx = (c * 256 + tid) * 16;            // byte within 16KB tile
            int row = idx >> 7, colb = idx & 127;
            int dst = idx ^ ((row & 7) << 4);
            uint4 va = *(const uint4*)((const char*)A + (size_t)(m0 + row) * 768 + kt * 128 + colb);
            *(uint4*)((char*)sa + dst) = va;
            uint4 vb = *(const uint4*)((const char*)Bm + (size_t)(n0 + row) * 768 + kt * 128 + colb);
            *(uint4*)((char*)sb + dst) = vb;
        }
        __syncthreads();
#pragma unroll
        for (int kc = 0; kc < 2; ++kc) {
            bf16x8 af[4], bf[4];
#pragma unroll
            for (int mt = 0; mt < 4; ++mt) {
                int row = wr * 64 + mt * 16 + (lane & 15);
                int off = (row * 128 + kc * 64 + (lane >> 4) * 16) ^ ((row & 7) << 4);
                af[mt] = *(const bf16x8*)((const char*)sa + off);
            }
#pragma unroll
            for (int nt = 0; nt < 4; ++nt) {
                int row = wc * 64 + nt * 16 + (lane & 15);
                int off = (row * 128 + kc * 64 + (lane >> 4) * 16) ^ ((row & 7) << 4);
                bf[nt] = *(const bf16x8*)((const char*)sb + off);
            }
#pragma unroll
            for (int mt = 0; mt < 4; ++mt)
#pragma unroll
                for (int nt = 0; nt < 4; ++nt)
                    acc[mt][nt] = __builtin_amdgcn_mfma_f32_16x16x32_bf16(af[mt], bf[nt], acc[mt][nt], 0, 0, 0);
        }
        __syncthreads();
    }
    // epilogue: tile spans exactly batch element b = blockIdx.y (t = 0..127)
    int b = blockIdx.y;
    int len = lengths[b];
    int grp = b >> 5, row32 = b & 31;
    int reg = (row32 >> 3) * 4 + (row32 & 3);
    int khb = (row32 >> 2) & 1;
    int ii = reg >> 1;
#pragma unroll
    for (int mt = 0; mt < 4; ++mt)
#pragma unroll
        for (int nt = 0; nt < 4; ++nt) {
            int col = n0 + wc * 64 + nt * 16 + (lane & 15);
            int dd = col >> 10, rem = col & 1023;
            int gate = rem >> 8, hid = rem & 255;
            int hb = hid >> 5, ho2 = hid & 31;
            int lane2 = khb * 32 + ho2;
            int w16 = (reg & 1) * 4 + gate;
#pragma unroll
            for (int r = 0; r < 4; ++r) {
                int t = wr * 64 + mt * 16 + (lane >> 4) * 4 + r;
                int tt = dd ? ((t < len) ? (len - 1 - t) : t) : t;
                size_t slot = (((((size_t)(dd * 4 + grp) * 128 + tt) * 8 + hb) * 8 + ii) * 64 + lane2) * 8 + w16;
                C[slot] = f2bf(acc[mt][nt][r]);
            }
        }
}

// ============================================================
// BiLSTM recurrence, zero cross-WG sync.
// 8 WGs = dir(2) x group(4, 32 batch rows). 512 threads = 8 waves, wave = hb.
// w_hh fp8: gates 0..2 register-resident (96 VGPR), gate 3 streamed from L2.
// h kept as fp8 in LDS (8KB, XOR-swizzled); c-state f32 in registers.
// MFMA: v_mfma_f32_32x32x16_fp8_fp8, 64 per wave per step.
// ============================================================
__global__ __launch_bounds__(512, 2) void k_lstm(const u16* __restrict__ xg2,
                                                 const u8* __restrict__ whh8,
                                                 const float* __restrict__ b_f,
                                                 const float* __restrict__ b_b,
                                                 const int* __restrict__ lengths,
                                                 u16* __restrict__ hs) {
    __shared__ u8 h8[8192];                            // [32 rows][256 hid] fp8, byte ^= row<<3
    int tid = threadIdx.x, lane = tid & 63, wave = tid >> 6;
    int dg = blockIdx.x;
    int d = dg >> 2, grp = dg & 3;
    int ho = lane & 31, kh = lane >> 5;
    int hid = (wave << 5) + ho;

    for (int i = tid * 16; i < 8192; i += 512 * 16) *(uint4*)(h8 + i) = (uint4){0, 0, 0, 0};

    const float* bias = d ? b_b : b_f;
    float bi = bias[hid], bff = bias[256 + hid], bgg = bias[512 + hid], bo = bias[768 + hid];

    u32 lenp[4];
#pragma unroll
    for (int j = 0; j < 4; ++j) {
        u32 v = 0;
#pragma unroll
        for (int q = 0; q < 4; ++q) {
            int row = q + 4 * kh + 8 * j;
            v |= ((u32)lengths[grp * 32 + row] & 255u) << (q * 8);
        }
        lenp[j] = v;
    }

    const u8* wbase = whh8 + ((size_t)((d * 8 + wave) * 4)) * 8192;
    u64x16 br0, br1, br2;
#pragma unroll
    for (int i = 0; i < 16; ++i) {
        br0[i] = *(const u64*)(wbase + (0 * 16 + i) * 512 + lane * 8);
        br1[i] = *(const u64*)(wbase + (1 * 16 + i) * 512 + lane * 8);
        br2[i] = *(const u64*)(wbase + (2 * 16 + i) * 512 + lane * 8);
    }
    const u8* wg3 = wbase + 3 * 8192;

    float cst[16];
#pragma unroll
    for (int i = 0; i < 16; ++i) cst[i] = 0.f;

    uint4 xq[8];
    {
        const u16* xb = xg2 + ((size_t)(dg * 128 + 0) * 8 + wave) * 4096;
#pragma unroll
        for (int i = 0; i < 8; ++i) xq[i] = *(const uint4*)(xb + (i * 64 + lane) * 8);
    }
    __syncthreads();

    for (int t = 0; t < 128; ++t) {
        f32x16 acc0, acc1, acc2, acc3;
#pragma unroll
        for (int i = 0; i < 16; ++i) { acc0[i] = 0.f; acc1[i] = 0.f; acc2[i] = 0.f; acc3[i] = 0.f; }

        u64 bs[16];
#pragma unroll
        for (int i = 0; i < 8; ++i) bs[i] = *(const u64*)(wg3 + i * 512 + lane * 8);

#pragma unroll
        for (int kc = 0; kc < 16; ++kc) {
            if (kc < 8) bs[kc + 8] = *(const u64*)(wg3 + (kc + 8) * 512 + lane * 8);
            long long a = *(const long long*)(h8 + (((ho << 8) + (kc << 4) + (kh << 3)) ^ (ho << 3)));
            acc0 = __builtin_amdgcn_mfma_f32_32x32x16_fp8_fp8(a, (long long)br0[kc], acc0, 0, 0, 0);
            acc1 = __builtin_amdgcn_mfma_f32_32x32x16_fp8_fp8(a, (long long)br1[kc], acc1, 0, 0, 0);
            acc2 = __builtin_amdgcn_mfma_f32_32x32x16_fp8_fp8(a, (long long)br2[kc], acc2, 0, 0, 0);
            acc3 = __builtin_amdgcn_mfma_f32_32x32x16_fp8_fp8(a, (long long)bs[kc], acc3, 0, 0, 0);
        }
        __syncthreads();                               // all h8 reads done before epilogue writes

        // pass 1: fold xg + bias into acc (frees xq for the prefetch)
#pragma unroll
        for (int reg = 0; reg < 16; ++reg) {
            uint4 q = xq[reg >> 1];
            u32 lo = (reg & 1) ? q.z : q.x;
            u32 hi2 = (reg & 1) ? q.w : q.y;
            acc0[reg] += bf2f((u16)(lo & 0xffff)) + bi;
            acc1[reg] += bf2f((u16)(lo >> 16)) + bff;
            acc2[reg] += bf2f((u16)(hi2 & 0xffff)) + bgg;
            acc3[reg] += bf2f((u16)(hi2 >> 16)) + bo;
        }
        if (t < 127) {                                 // prefetch next step's xg
            const u16* xb = xg2 + ((size_t)(dg * 128 + (t + 1)) * 8 + wave) * 4096;
#pragma unroll
            for (int i = 0; i < 8; ++i) xq[i] = *(const uint4*)(xb + (i * 64 + lane) * 8);
        }
        // pass 2: activations + state update
#pragma unroll
        for (int reg = 0; reg < 16; ++reg) {
            int row = (reg & 3) + 4 * kh + 8 * (reg >> 2);
            int len = (int)((lenp[reg >> 2] >> ((reg & 3) * 8)) & 255u);
            float gi = sigm(acc0[reg]);
            float gf = sigm(acc1[reg]);
            float gg = tanh_(acc2[reg]);
            float go = sigm(acc3[reg]);
            float cn = gf * cst[reg] + gi * gg;
            float hn = go * tanh_(cn);
            if (t < len) {
                cst[reg] = cn;
                h8[((row << 8) + hid) ^ (row << 3)] = f2fp8(hn);
                int pout = d ? (len - 1 - t) : t;
                hs[(((size_t)((grp * 32 + row) * 128 + pout)) << 9) + (d << 8) + hid] = f2bf(hn);
            }
        }
        __syncthreads();
    }
}

// ============================================================
// Emissions: emis[pos][17] = hs[pos][512] . proj_w[17][512] + proj_b
// ============================================================
__global__ __launch_bounds__(256) void k_emis(const u16* __restrict__ hs,
                                              const float* __restrict__ proj_w,
                                              const float* __restrict__ proj_b,
                                              float* __restrict__ emis) {
    __shared__ float pw[17 * 512];
    int tid = threadIdx.x;
    for (int i = tid; i < 17 * 512; i += 256) pw[i] = proj_w[i];
    __syncthreads();
    int lane = tid & 63, wv = tid >> 6;
    int pos = blockIdx.x * 4 + wv;
    float hv[8];
    const u16* hp = hs + (size_t)pos * 512 + lane * 8;
#pragma unroll
    for (int j = 0; j < 8; ++j) hv[j] = bf2f(hp[j]);
    for (int tg = 0; tg < 17; ++tg) {
        const float* wp = pw + tg * 512 + lane * 8;
        float s = 0.f;
#pragma unroll
        for (int j = 0; j < 8; ++j) s = fmaf(hv[j], wp[j], s);
#pragma unroll
        for (int off = 32; off; off >>= 1) s += __shfl_down(s, off);
        if (lane == 0) emis[(size_t)pos * 17 + tg] = s + proj_b[tg];
    }
}

// ============================================================
// CRF per-sample NLL. One 64-thread block per batch element.
// ============================================================
__global__ __launch_bounds__(64) void k_crf(const float* __restrict__ emis,
                                            const int* __restrict__ tags,
                                            const int* __restrict__ lengths,
                                            const float* __restrict__ trans,
                                            const float* __restrict__ start_trans,
                                            const float* __restrict__ end_trans,
                                            float* __restrict__ nll) {
    int b = blockIdx.x, lane = threadIdx.x;
    __shared__ float tr[289];
    __shared__ float al[17];
    __shared__ float scs;
    for (int i = lane; i < 289; i += 64) tr[i] = trans[i];
    int len = lengths[b];
    const int* tg = tags + (size_t)b * 128;
    const float* em = emis + (size_t)b * 128 * 17;
    __syncthreads();

    float sc = 0.f;
    for (int t = lane; t < len; t += 64) {
        sc += em[t * 17 + tg[t]];
        if (t >= 1) sc += tr[tg[t - 1] * 17 + tg[t]];
    }
#pragma unroll
    for (int off = 32; off; off >>= 1) sc += __shfl_down(sc, off);
    if (lane == 0) scs = sc + start_trans[tg[0]] + end_trans[tg[len - 1]];

    if (lane < 17) al[lane] = start_trans[lane] + em[lane];
    __syncthreads();
    for (int t = 1; t < len; ++t) {
        float anew = 0.f;
        if (lane < 17) {
            float m = -1e30f;
            for (int i = 0; i < 17; ++i) m = fmaxf(m, al[i] + tr[i * 17 + lane]);
            float s = 0.f;
            for (int i = 0; i < 17; ++i) s += __expf(al[i] + tr[i * 17 + lane] - m);
            anew = m + __logf(s) + em[t * 17 + lane];
        }
        __syncthreads();
        if (lane < 17) al[lane] = anew;
        __syncthreads();
    }
    float v = (lane < 17) ? al[lane] + end_trans[lane] : -1e30f;
    float m = v;
#pragma unroll
    for (int off = 32; off; off >>= 1) m = fmaxf(m, __shfl_xor(m, off));
    float s = (lane < 17) ? __expf(v - m) : 0.f;
#pragma unroll
    for (int off = 32; off; off >>= 1) s += __shfl_xor(s, off);
    if (lane == 0) nll[b] = (m + __logf(s)) - scs;
}

__global__ __launch_bounds__(128) void k_reduce(const float* __restrict__ nll, float* __restrict__ out) {
    int tid = threadIdx.x;
    float v = nll[tid];
#pragma unroll
    for (int off = 32; off; off >>= 1) v += __shfl_down(v, off);
    __shared__ float partial[2];
    if ((tid & 63) == 0) partial[tid >> 6] = v;
    __syncthreads();
    if (tid == 0) out[0] = partial[0] + partial[1];
}

// ============================================================
extern "C" void kernel_launch(void* const* d_in, const int* in_sizes, int n_in,
                              void* d_out, int out_size, void* d_ws, size_t ws_size,
                              hipStream_t stream) {
    (void)in_sizes; (void)n_in; (void)out_size; (void)ws_size;
    const int*   words       = (const int*)d_in[0];
    const int*   chars       = (const int*)d_in[1];
    const int*   tags        = (const int*)d_in[2];
    const int*   lengths     = (const int*)d_in[3];
    const float* word_emb    = (const float*)d_in[4];
    const float* char_emb    = (const float*)d_in[5];
    const float* conv_w      = (const float*)d_in[6];
    const float* conv_b      = (const float*)d_in[7];
    const float* w_ih_f      = (const float*)d_in[8];
    const float* w_hh_f      = (const float*)d_in[9];
    const float* b_f         = (const float*)d_in[10];
    const float* w_ih_b      = (const float*)d_in[11];
    const float* w_hh_b      = (const float*)d_in[12];
    const float* b_b         = (const float*)d_in[13];
    const float* proj_w      = (const float*)d_in[14];
    const float* proj_b      = (const float*)d_in[15];
    const float* trans       = (const float*)d_in[16];
    const float* start_trans = (const float*)d_in[17];
    const float* end_trans   = (const float*)d_in[18];

    char* ws = (char*)d_ws;
    u16* inp   = (u16*)(ws + OFF_INP);
    u16* wih   = (u16*)(ws + OFF_WIH);
    u8*  whh8  = (u8*)(ws + OFF_WHH);
    u16* xgb   = (u16*)(ws + OFF_XG);
    u16* hsb   = (u16*)(ws + OFF_HS);
    float* em  = (float*)(ws + OFF_EMIS);
    float* nll = (float*)(ws + OFF_NLL);

    k_prep_wih<<<2048, 128, 0, stream>>>(w_ih_f, w_ih_b, wih);
    k_prep_whh8<<<2048, 128, 0, stream>>>(w_hh_f, w_hh_b, whh8);
    k_embed_conv<<<NPOS, 128, 0, stream>>>(words, chars, word_emb, char_emb, conv_w, conv_b, inp);
    k_gemm<<<dim3(16, 128), 256, 0, stream>>>(inp, wih, xgb, lengths);
    k_lstm<<<8, 512, 0, stream>>>(xgb, whh8, b_f, b_b, lengths, hsb);
    k_emis<<<4096, 256, 0, stream>>>(hsb, proj_w, proj_b, em);
    k_crf<<<128, 64, 0, stream>>>(em, tags, lengths, trans, start_trans, end_trans, nll);
    k_reduce<<<1, 128, 0, stream>>>(nll, (float*)d_out);
}

// Round 4
// 864.371 us; speedup vs baseline: 1.9800x; 1.9800x over previous
//
#include <hip/hip_runtime.h>
#include <stdint.h>

typedef unsigned char u8;
typedef unsigned short u16;
typedef unsigned int u32;
typedef unsigned long long u64;

// ---- problem constants ----
// B=128 S=128 WL=16 V=50000 C=100 T=17 WE=300 CE=50 CF=50 K=3 H=256 D=350
#define NPOS 16384          // B*S
#define KPAD 384            // D padded to multiple of 64

typedef __attribute__((ext_vector_type(8))) short bf16x8;
typedef __attribute__((ext_vector_type(4))) float f32x4;

__device__ __forceinline__ float bf2f(u16 u) { return __uint_as_float(((u32)u) << 16); }
__device__ __forceinline__ u16 f2bf(float f) {
    u32 u = __float_as_uint(f);
    u += 0x7fffu + ((u >> 16) & 1u);   // RNE
    return (u16)(u >> 16);
}
__device__ __forceinline__ float sigm(float x) { return 1.0f / (1.0f + __expf(-x)); }
__device__ __forceinline__ float tanh_(float x) { return 2.0f / (1.0f + __expf(-2.0f * x)) - 1.0f; }

// f32 -> fp8 e4m3fn (OCP), RNE, clamp to +-448. Prep-path (manual, no builtin risk).
__device__ u8 f2fp8_manual(float f) {
    u32 u = __float_as_uint(f);
    u32 s = (u >> 31) << 7;
    u32 ae = (u >> 23) & 255u;
    u32 m = u & 0x7fffffu;
    int e = (int)ae - 127;
    if (ae == 0) return (u8)s;                 // f32 subnormal -> 0
    if (e >= 9) return (u8)(s | 0x7e);         // >= 512 -> clamp 448
    if (e >= -6) {                             // e4m3 normal
        u32 mant = m >> 20;
        u32 rem = m & 0xfffffu;
        if (rem > 0x80000u || (rem == 0x80000u && (mant & 1u))) mant++;
        u32 ef = (u32)(e + 7);
        if (mant == 8u) { mant = 0u; ef++; }
        if (ef >= 16u || (ef == 15u && mant == 7u)) return (u8)(s | 0x7e);
        return (u8)(s | (ef << 3) | mant);
    }
    if (e < -10) return (u8)s;                 // underflow to 0
    int sb = 14 - e;                           // shift for units of 2^-9
    u32 X = 0x800000u | m;
    u32 mant = X >> sb;
    u32 rem = X & ((1u << sb) - 1u);
    u32 half = 1u << (sb - 1);
    if (rem > half || (rem == half && (mant & 1u))) mant++;
    if (mant >= 8u) return (u8)(s | (1u << 3)); // rounds to first normal 2^-6
    return (u8)(s | mant);
}

__device__ __forceinline__ u8 f2fp8(float f) {
#if __has_builtin(__builtin_amdgcn_cvt_pk_fp8_f32)
    return (u8)(__builtin_amdgcn_cvt_pk_fp8_f32(f, f, 0, false) & 0xff);
#else
    return f2fp8_manual(f);
#endif
}

// ---- workspace layout (bytes) ----
static constexpr size_t OFF_INP  = 0;                       // u16 [16384][384]   = 12582912
static constexpr size_t OFF_WIH  = 12582912;                // u16 [2048][384]    = 1572864
static constexpr size_t OFF_WHH  = 14155776;                // fp8 packed 512KB
static constexpr size_t OFF_XG   = 15204352;                // u16 xg2 repacked   = 67108864
static constexpr size_t OFF_HS   = 82313216;                // u16 [16384][512]   = 16777216
static constexpr size_t OFF_EMIS = 99090432;                // f32 [16384][17]    = 1114112
static constexpr size_t OFF_NLL  = 100204544;               // f32 [128]

// ============================================================
// Prep: pack [w_ih_f; w_ih_b] into bf16 [2048][384] (K padded w/ zeros)
// ============================================================
__global__ __launch_bounds__(128) void k_prep_wih(const float* __restrict__ wf,
                                                  const float* __restrict__ wb,
                                                  u16* __restrict__ wih) {
    int n = blockIdx.x, tid = threadIdx.x;
    const float* src = (n < 1024) ? (wf + (size_t)n * 350) : (wb + (size_t)(n - 1024) * 350);
    u16* dst = wih + (size_t)n * KPAD;
    for (int k = tid; k < KPAD; k += 128) dst[k] = (k < 350) ? f2bf(src[k]) : (u16)0;
}

// ============================================================
// Prep: w_hh (both dirs) -> fp8, packed for 16x16x32 B-frags:
// whh8[((d*8+w)*4+g)*8192 + (nb*8+kc)*512 + (q*16+c16)*8 + e]
// where hid = w*32+nb*16+c16, k = kc*32 + q*8 + e
// ============================================================
__global__ __launch_bounds__(128) void k_prep_whh8(const float* __restrict__ wf,
                                                   const float* __restrict__ wb,
                                                   u8* __restrict__ whh8) {
    int bx = blockIdx.x, tid = threadIdx.x;
    int d = bx >> 10, row = bx & 1023;                 // row = gate*256 + hid
    const float* src = (d ? wb : wf) + (size_t)row * 256;
    int g = row >> 8, hid = row & 255;
    int w = hid >> 5, nb = (hid >> 4) & 1, c16 = hid & 15;
    u8* base = whh8 + ((size_t)((d * 8 + w) * 4 + g)) * 8192;
    for (int k = tid; k < 256; k += 128) {
        int kc = k >> 5, q = (k >> 3) & 3, e = k & 7;
        base[(nb * 8 + kc) * 512 + (q * 16 + c16) * 8 + e] = f2fp8_manual(src[k]);
    }
}

// ============================================================
// Embedding + char conv + concat -> inp bf16 [16384][384]
// ============================================================
__global__ __launch_bounds__(128) void k_embed_conv(const int* __restrict__ words,
                                                    const int* __restrict__ chars,
                                                    const float* __restrict__ word_emb,
                                                    const float* __restrict__ char_emb,
                                                    const float* __restrict__ conv_w,
                                                    const float* __restrict__ conv_b,
                                                    u16* __restrict__ inp) {
    int pos = blockIdx.x, tid = threadIdx.x;
    __shared__ float ce[18 * 50];                      // rows 0 and 17 are zero pad
    const int* ch = chars + (size_t)pos * 16;
    for (int i = tid; i < 18 * 50; i += 128) {
        int row = i / 50, c = i - row * 50;
        float v = 0.f;
        if (row >= 1 && row <= 16) v = char_emb[(size_t)ch[row - 1] * 50 + c];
        ce[i] = v;
    }
    __syncthreads();
    {   // word embedding copy + zero pad
        const float* we = word_emb + (size_t)words[pos] * 300;
        u16* op = inp + (size_t)pos * KPAD;
        for (int c = tid; c < 300; c += 128) op[c] = f2bf(we[c]);
        for (int c = 350 + tid; c < KPAD; c += 128) op[c] = 0;
    }
    if (tid < 100) {
        int oc = tid >> 1, half = tid & 1, t0 = half * 8;
        float acc[8];
#pragma unroll
        for (int tt = 0; tt < 8; ++tt) acc[tt] = 0.f;
        const float* wrow = conv_w + (size_t)oc * 150;
        for (int ic = 0; ic < 50; ++ic) {
#pragma unroll
            for (int k = 0; k < 3; ++k) {
                float wv = wrow[ic * 3 + k];
#pragma unroll
                for (int tt = 0; tt < 8; ++tt)
                    acc[tt] = fmaf(ce[(t0 + tt + k) * 50 + ic], wv, acc[tt]);
            }
        }
        float cb = conv_b[oc];
        float m = 0.f;                                  // relu floor
#pragma unroll
        for (int tt = 0; tt < 8; ++tt) m = fmaxf(m, acc[tt] + cb);
        m = fmaxf(m, __shfl_xor(m, 1));
        if (half == 0) inp[(size_t)pos * KPAD + 300 + oc] = f2bf(m);
    }
}

// ============================================================
// GEMM: inp[16384][384] @ wih[2048][384]^T (bf16 MFMA). Epilogue writes xg2
// packed for k_lstm's 16-row groups:
// slot = ((d*8+grp)*128 + tt)*16384 + (w*64 + q*16 + c16)*32 + (nb*4+reg)*4 + gate
// with bwd time axis pre-reversed (tt).
// ============================================================
__global__ __launch_bounds__(256, 2) void k_gemm(const u16* __restrict__ A,
                                                 const u16* __restrict__ Bm,
                                                 u16* __restrict__ C,
                                                 const int* __restrict__ lengths) {
    __shared__ u16 sa[128 * 64];
    __shared__ u16 sb[128 * 64];
    int tid = threadIdx.x;
    int n0 = blockIdx.x * 128, m0 = blockIdx.y * 128;
    int lane = tid & 63, wid = tid >> 6;
    int wr = wid >> 1, wc = wid & 1;
    f32x4 acc[4][4];
#pragma unroll
    for (int mt = 0; mt < 4; ++mt)
#pragma unroll
        for (int nt = 0; nt < 4; ++nt) acc[mt][nt] = (f32x4){0.f, 0.f, 0.f, 0.f};

    for (int kt = 0; kt < 6; ++kt) {
#pragma unroll
        for (int c = 0; c < 4; ++c) {
            int idx = (c * 256 + tid) * 16;            // byte within 16KB tile
            int row = idx >> 7, colb = idx & 127;
            int dst = idx ^ ((row & 7) << 4);
            uint4 va = *(const uint4*)((const char*)A + (size_t)(m0 + row) * 768 + kt * 128 + colb);
            *(uint4*)((char*)sa + dst) = va;
            uint4 vb = *(const uint4*)((const char*)Bm + (size_t)(n0 + row) * 768 + kt * 128 + colb);
            *(uint4*)((char*)sb + dst) = vb;
        }
        __syncthreads();
#pragma unroll
        for (int kc = 0; kc < 2; ++kc) {
            bf16x8 af[4], bf[4];
#pragma unroll
            for (int mt = 0; mt < 4; ++mt) {
                int row = wr * 64 + mt * 16 + (lane & 15);
                int off = (row * 128 + kc * 64 + (lane >> 4) * 16) ^ ((row & 7) << 4);
                af[mt] = *(const bf16x8*)((const char*)sa + off);
            }
#pragma unroll
            for (int nt = 0; nt < 4; ++nt) {
                int row = wc * 64 + nt * 16 + (lane & 15);
                int off = (row * 128 + kc * 64 + (lane >> 4) * 16) ^ ((row & 7) << 4);
                bf[nt] = *(const bf16x8*)((const char*)sb + off);
            }
#pragma unroll
            for (int mt = 0; mt < 4; ++mt)
#pragma unroll
                for (int nt = 0; nt < 4; ++nt)
                    acc[mt][nt] = __builtin_amdgcn_mfma_f32_16x16x32_bf16(af[mt], bf[nt], acc[mt][nt], 0, 0, 0);
        }
        __syncthreads();
    }
    // epilogue: tile spans exactly batch element b = blockIdx.y (t = 0..127)
    int b = blockIdx.y;
    int len = lengths[b];
    int grp = b >> 4, row16 = b & 15;
    int qq = row16 >> 2, rg = row16 & 3;
#pragma unroll
    for (int mt = 0; mt < 4; ++mt)
#pragma unroll
        for (int nt = 0; nt < 4; ++nt) {
            int col = n0 + wc * 64 + nt * 16 + (lane & 15);
            int dd = col >> 10, rem = col & 1023;
            int gate = rem >> 8, hid = rem & 255;
            int w2 = hid >> 5, nb = (hid >> 4) & 1, cc = hid & 15;
            int loff = (w2 * 64 + qq * 16 + cc) * 32 + (nb * 4 + rg) * 4 + gate;
#pragma unroll
            for (int r = 0; r < 4; ++r) {
                int t = wr * 64 + mt * 16 + (lane >> 4) * 4 + r;
                int tt = dd ? ((t < len) ? (len - 1 - t) : t) : t;
                size_t slot = ((size_t)(dd * 8 + grp) * 128 + tt) * 16384 + loff;
                C[slot] = f2bf(acc[mt][nt][r]);
            }
        }
}

// ============================================================
// BiLSTM recurrence, zero cross-WG sync, register-budgeted.
// 16 WGs = dir(2) x group(8, 16 batch rows). 512 threads = 8 waves; wave w owns
// hid block [32w, 32w+32). All 4 gates' w_hh register-resident as fp8
// (u64 br[4][16] = 128 VGPRs). h fp8 in LDS (4KB, XOR-swizzled).
// MFMA: v_mfma_f32_16x16x32_fp8_fp8 (M=16 rows, N=16 hid, K=32).
// ============================================================
__global__ __launch_bounds__(512, 2) void k_lstm(const u16* __restrict__ xg2,
                                                 const u8* __restrict__ whh8,
                                                 const float* __restrict__ b_f,
                                                 const float* __restrict__ b_b,
                                                 const int* __restrict__ lengths,
                                                 u16* __restrict__ hs) {
    __shared__ u8 h8[4096];                            // [16 rows][256 hid], byte: r*256 + (k ^ ((r&7)<<3))
    int tid = threadIdx.x, lane = tid & 63, w = tid >> 6;
    int bx = blockIdx.x;
    int d = bx >> 3, grp = bx & 7;
    int c16 = lane & 15, q = lane >> 4;

    ((u64*)h8)[tid] = 0;                               // 512*8 = 4096

    const float* bias = d ? b_b : b_f;
    float bia[2][4];
#pragma unroll
    for (int nb = 0; nb < 2; ++nb) {
        int hid = w * 32 + nb * 16 + c16;
#pragma unroll
        for (int g = 0; g < 4; ++g) bia[nb][g] = bias[g * 256 + hid];
    }
    int lenr[4];
#pragma unroll
    for (int rg = 0; rg < 4; ++rg) lenr[rg] = lengths[grp * 16 + q * 4 + rg];

    // register-resident fp8 weights: 4 gates x 16 (nb*8+kc) u64 frags = 128 VGPRs
    const u8* wbse = whh8 + ((size_t)((d * 8 + w) * 4)) * 8192;
    u64 br[4][16];
#pragma unroll
    for (int g = 0; g < 4; ++g)
#pragma unroll
        for (int j = 0; j < 16; ++j)
            br[g][j] = *(const u64*)(wbse + (size_t)g * 8192 + j * 512 + lane * 8);

    float cst[8];
#pragma unroll
    for (int u = 0; u < 8; ++u) cst[u] = 0.f;

    // xg prefetch: 64B/lane = 4 uint4 = [unit(8)][gate(4)] u16
    const u16* xslab = xg2 + ((size_t)(d * 8 + grp) * 128) * 16384 + (w * 64 + lane) * 32;
    uint4 xq[4];
#pragma unroll
    for (int i = 0; i < 4; ++i) xq[i] = *(const uint4*)(xslab + i * 8);

    // A-frag LDS addressing (row r = c16, k = kc*32 + q*8 + e)
    int abase = c16 * 256, aswz = (c16 & 7) << 3, akoff = q * 8;

    __syncthreads();

    for (int t = 0; t < 128; ++t) {
        f32x4 acc[8];
#pragma unroll
        for (int u = 0; u < 8; ++u) acc[u] = (f32x4){0.f, 0.f, 0.f, 0.f};

#pragma unroll
        for (int kc = 0; kc < 8; ++kc) {
            long long a = *(const long long*)(h8 + abase + ((kc * 32 + akoff) ^ aswz));
#pragma unroll
            for (int nb = 0; nb < 2; ++nb)
#pragma unroll
                for (int g = 0; g < 4; ++g)
                    acc[nb * 4 + g] = __builtin_amdgcn_mfma_f32_16x16x32_fp8_fp8(
                        a, (long long)br[g][nb * 8 + kc], acc[nb * 4 + g], 0, 0, 0);
        }
        __syncthreads();                               // all h8 reads done before writes

        // unpack xq into u32 words (static indices), then prefetch next step
        u32 xw[16];
#pragma unroll
        for (int i = 0; i < 4; ++i) {
            xw[i * 4 + 0] = xq[i].x; xw[i * 4 + 1] = xq[i].y;
            xw[i * 4 + 2] = xq[i].z; xw[i * 4 + 3] = xq[i].w;
        }
        if (t < 127) {
            const u16* xb = xslab + (size_t)(t + 1) * 16384;
#pragma unroll
            for (int i = 0; i < 4; ++i) xq[i] = *(const uint4*)(xb + i * 8);
        }

#pragma unroll
        for (int nb = 0; nb < 2; ++nb)
#pragma unroll
            for (int rg = 0; rg < 4; ++rg) {
                int u = nb * 4 + rg;
                float pi = acc[nb * 4 + 0][rg] + bf2f((u16)(xw[u * 2] & 0xffff)) + bia[nb][0];
                float pf = acc[nb * 4 + 1][rg] + bf2f((u16)(xw[u * 2] >> 16)) + bia[nb][1];
                float pg = acc[nb * 4 + 2][rg] + bf2f((u16)(xw[u * 2 + 1] & 0xffff)) + bia[nb][2];
                float po = acc[nb * 4 + 3][rg] + bf2f((u16)(xw[u * 2 + 1] >> 16)) + bia[nb][3];
                float gi = sigm(pi);
                float gf = sigm(pf);
                float gg = tanh_(pg);
                float go = sigm(po);
                float cn = gf * cst[u] + gi * gg;
                float hn = go * tanh_(cn);
                int len = lenr[rg];
                if (t < len) {
                    cst[u] = cn;
                    int row = q * 4 + rg;
                    int hid = w * 32 + nb * 16 + c16;
                    h8[row * 256 + (hid ^ ((row & 7) << 3))] = f2fp8(hn);
                    int pout = d ? (len - 1 - t) : t;
                    hs[((size_t)((grp * 16 + row) * 128 + pout)) * 512 + d * 256 + hid] = f2bf(hn);
                }
            }
        __syncthreads();
    }
}

// ============================================================
// Emissions: emis[pos][17] = hs[pos][512] . proj_w[17][512] + proj_b
// ============================================================
__global__ __launch_bounds__(256) void k_emis(const u16* __restrict__ hs,
                                              const float* __restrict__ proj_w,
                                              const float* __restrict__ proj_b,
                                              float* __restrict__ emis) {
    __shared__ float pw[17 * 512];
    int tid = threadIdx.x;
    for (int i = tid; i < 17 * 512; i += 256) pw[i] = proj_w[i];
    __syncthreads();
    int lane = tid & 63, wv = tid >> 6;
    int pos = blockIdx.x * 4 + wv;
    float hv[8];
    const u16* hp = hs + (size_t)pos * 512 + lane * 8;
#pragma unroll
    for (int j = 0; j < 8; ++j) hv[j] = bf2f(hp[j]);
    for (int tg = 0; tg < 17; ++tg) {
        const float* wp = pw + tg * 512 + lane * 8;
        float s = 0.f;
#pragma unroll
        for (int j = 0; j < 8; ++j) s = fmaf(hv[j], wp[j], s);
#pragma unroll
        for (int off = 32; off; off >>= 1) s += __shfl_down(s, off);
        if (lane == 0) emis[(size_t)pos * 17 + tg] = s + proj_b[tg];
    }
}

// ============================================================
// CRF per-sample NLL. One 64-thread block per batch element.
// ============================================================
__global__ __launch_bounds__(64) void k_crf(const float* __restrict__ emis,
                                            const int* __restrict__ tags,
                                            const int* __restrict__ lengths,
                                            const float* __restrict__ trans,
                                            const float* __restrict__ start_trans,
                                            const float* __restrict__ end_trans,
                                            float* __restrict__ nll) {
    int b = blockIdx.x, lane = threadIdx.x;
    __shared__ float tr[289];
    __shared__ float al[17];
    __shared__ float scs;
    for (int i = lane; i < 289; i += 64) tr[i] = trans[i];
    int len = lengths[b];
    const int* tg = tags + (size_t)b * 128;
    const float* em = emis + (size_t)b * 128 * 17;
    __syncthreads();

    float sc = 0.f;
    for (int t = lane; t < len; t += 64) {
        sc += em[t * 17 + tg[t]];
        if (t >= 1) sc += tr[tg[t - 1] * 17 + tg[t]];
    }
#pragma unroll
    for (int off = 32; off; off >>= 1) sc += __shfl_down(sc, off);
    if (lane == 0) scs = sc + start_trans[tg[0]] + end_trans[tg[len - 1]];

    if (lane < 17) al[lane] = start_trans[lane] + em[lane];
    __syncthreads();
    for (int t = 1; t < len; ++t) {
        float anew = 0.f;
        if (lane < 17) {
            float m = -1e30f;
            for (int i = 0; i < 17; ++i) m = fmaxf(m, al[i] + tr[i * 17 + lane]);
            float s = 0.f;
            for (int i = 0; i < 17; ++i) s += __expf(al[i] + tr[i * 17 + lane] - m);
            anew = m + __logf(s) + em[t * 17 + lane];
        }
        __syncthreads();
        if (lane < 17) al[lane] = anew;
        __syncthreads();
    }
    float v = (lane < 17) ? al[lane] + end_trans[lane] : -1e30f;
    float m = v;
#pragma unroll
    for (int off = 32; off; off >>= 1) m = fmaxf(m, __shfl_xor(m, off));
    float s = (lane < 17) ? __expf(v - m) : 0.f;
#pragma unroll
    for (int off = 32; off; off >>= 1) s += __shfl_xor(s, off);
    if (lane == 0) nll[b] = (m + __logf(s)) - scs;
}

__global__ __launch_bounds__(128) void k_reduce(const float* __restrict__ nll, float* __restrict__ out) {
    int tid = threadIdx.x;
    float v = nll[tid];
#pragma unroll
    for (int off = 32; off; off >>= 1) v += __shfl_down(v, off);
    __shared__ float partial[2];
    if ((tid & 63) == 0) partial[tid >> 6] = v;
    __syncthreads();
    if (tid == 0) out[0] = partial[0] + partial[1];
}

// ============================================================
extern "C" void kernel_launch(void* const* d_in, const int* in_sizes, int n_in,
                              void* d_out, int out_size, void* d_ws, size_t ws_size,
                              hipStream_t stream) {
    (void)in_sizes; (void)n_in; (void)out_size; (void)ws_size;
    const int*   words       = (const int*)d_in[0];
    const int*   chars       = (const int*)d_in[1];
    const int*   tags        = (const int*)d_in[2];
    const int*   lengths     = (const int*)d_in[3];
    const float* word_emb    = (const float*)d_in[4];
    const float* char_emb    = (const float*)d_in[5];
    const float* conv_w      = (const float*)d_in[6];
    const float* conv_b      = (const float*)d_in[7];
    const float* w_ih_f      = (const float*)d_in[8];
    const float* w_hh_f      = (const float*)d_in[9];
    const float* b_f         = (const float*)d_in[10];
    const float* w_ih_b      = (const float*)d_in[11];
    const float* w_hh_b      = (const float*)d_in[12];
    const float* b_b         = (const float*)d_in[13];
    const float* proj_w      = (const float*)d_in[14];
    const float* proj_b      = (const float*)d_in[15];
    const float* trans       = (const float*)d_in[16];
    const float* start_trans = (const float*)d_in[17];
    const float* end_trans   = (const float*)d_in[18];

    char* ws = (char*)d_ws;
    u16* inp   = (u16*)(ws + OFF_INP);
    u16* wih   = (u16*)(ws + OFF_WIH);
    u8*  whh8  = (u8*)(ws + OFF_WHH);
    u16* xgb   = (u16*)(ws + OFF_XG);
    u16* hsb   = (u16*)(ws + OFF_HS);
    float* em  = (float*)(ws + OFF_EMIS);
    float* nll = (float*)(ws + OFF_NLL);

    k_prep_wih<<<2048, 128, 0, stream>>>(w_ih_f, w_ih_b, wih);
    k_prep_whh8<<<2048, 128, 0, stream>>>(w_hh_f, w_hh_b, whh8);
    k_embed_conv<<<NPOS, 128, 0, stream>>>(words, chars, word_emb, char_emb, conv_w, conv_b, inp);
    k_gemm<<<dim3(16, 128), 256, 0, stream>>>(inp, wih, xgb, lengths);
    k_lstm<<<16, 512, 0, stream>>>(xgb, whh8, b_f, b_b, lengths, hsb);
    k_emis<<<4096, 256, 0, stream>>>(hsb, proj_w, proj_b, em);
    k_crf<<<128, 64, 0, stream>>>(em, tags, lengths, trans, start_trans, end_trans, nll);
    k_reduce<<<1, 128, 0, stream>>>(nll, (float*)d_out);
}

// Round 5
// 851.559 us; speedup vs baseline: 2.0098x; 1.0150x over previous
//
#include <hip/hip_runtime.h>
#include <stdint.h>

typedef unsigned char u8;
typedef unsigned short u16;
typedef unsigned int u32;
typedef unsigned long long u64;

// ---- problem constants ----
// B=128 S=128 WL=16 V=50000 C=100 T=17 WE=300 CE=50 CF=50 K=3 H=256 D=350
#define NPOS 16384          // B*S
#define KPAD 384            // D padded to multiple of 64

typedef __attribute__((ext_vector_type(8))) short bf16x8;
typedef __attribute__((ext_vector_type(4))) float f32x4;

__device__ __forceinline__ float bf2f(u16 u) { return __uint_as_float(((u32)u) << 16); }
__device__ __forceinline__ u16 f2bf(float f) {
    u32 u = __float_as_uint(f);
    u += 0x7fffu + ((u >> 16) & 1u);   // RNE
    return (u16)(u >> 16);
}
__device__ __forceinline__ float sigm(float x) { return 1.0f / (1.0f + __expf(-x)); }
__device__ __forceinline__ float tanh_(float x) { return 2.0f / (1.0f + __expf(-2.0f * x)) - 1.0f; }

// f32 -> fp8 e4m3fn (OCP), RNE, clamp to +-448. Prep-path (manual, no builtin risk).
__device__ u8 f2fp8_manual(float f) {
    u32 u = __float_as_uint(f);
    u32 s = (u >> 31) << 7;
    u32 ae = (u >> 23) & 255u;
    u32 m = u & 0x7fffffu;
    int e = (int)ae - 127;
    if (ae == 0) return (u8)s;                 // f32 subnormal -> 0
    if (e >= 9) return (u8)(s | 0x7e);         // >= 512 -> clamp 448
    if (e >= -6) {                             // e4m3 normal
        u32 mant = m >> 20;
        u32 rem = m & 0xfffffu;
        if (rem > 0x80000u || (rem == 0x80000u && (mant & 1u))) mant++;
        u32 ef = (u32)(e + 7);
        if (mant == 8u) { mant = 0u; ef++; }
        if (ef >= 16u || (ef == 15u && mant == 7u)) return (u8)(s | 0x7e);
        return (u8)(s | (ef << 3) | mant);
    }
    if (e < -10) return (u8)s;                 // underflow to 0
    int sb = 14 - e;                           // shift for units of 2^-9
    u32 X = 0x800000u | m;
    u32 mant = X >> sb;
    u32 rem = X & ((1u << sb) - 1u);
    u32 half = 1u << (sb - 1);
    if (rem > half || (rem == half && (mant & 1u))) mant++;
    if (mant >= 8u) return (u8)(s | (1u << 3)); // rounds to first normal 2^-6
    return (u8)(s | mant);
}

__device__ __forceinline__ u8 f2fp8(float f) {
#if __has_builtin(__builtin_amdgcn_cvt_pk_fp8_f32)
    return (u8)(__builtin_amdgcn_cvt_pk_fp8_f32(f, f, 0, false) & 0xff);
#else
    return f2fp8_manual(f);
#endif
}

// ---- workspace layout (bytes) ----
static constexpr size_t OFF_INP  = 0;                       // u16 [16384][384]   = 12582912
static constexpr size_t OFF_WIH  = 12582912;                // u16 [2048][384]    = 1572864
static constexpr size_t OFF_WHH  = 14155776;                // fp8 packed 512KB
static constexpr size_t OFF_XG   = 15204352;                // u16 xg2 repacked   = 67108864
static constexpr size_t OFF_HS   = 82313216;                // u16 [16384][512]   = 16777216
static constexpr size_t OFF_EMIS = 99090432;                // f32 [16384][17]    = 1114112
static constexpr size_t OFF_NLL  = 100204544;               // f32 [128]

// ============================================================
// Prep: pack [w_ih_f; w_ih_b] into bf16 [2048][384] (K padded w/ zeros)
// ============================================================
__global__ __launch_bounds__(128) void k_prep_wih(const float* __restrict__ wf,
                                                  const float* __restrict__ wb,
                                                  u16* __restrict__ wih) {
    int n = blockIdx.x, tid = threadIdx.x;
    const float* src = (n < 1024) ? (wf + (size_t)n * 350) : (wb + (size_t)(n - 1024) * 350);
    u16* dst = wih + (size_t)n * KPAD;
    for (int k = tid; k < KPAD; k += 128) dst[k] = (k < 350) ? f2bf(src[k]) : (u16)0;
}

// ============================================================
// Prep: w_hh (both dirs) -> fp8, packed for 16x16x32 B-frags:
// whh8[((d*8+w)*4+g)*8192 + (nb*8+kc)*512 + (q*16+c16)*8 + e]
// where hid = w*32+nb*16+c16, k = kc*32 + q*8 + e
// ============================================================
__global__ __launch_bounds__(128) void k_prep_whh8(const float* __restrict__ wf,
                                                   const float* __restrict__ wb,
                                                   u8* __restrict__ whh8) {
    int bx = blockIdx.x, tid = threadIdx.x;
    int d = bx >> 10, row = bx & 1023;                 // row = gate*256 + hid
    const float* src = (d ? wb : wf) + (size_t)row * 256;
    int g = row >> 8, hid = row & 255;
    int w = hid >> 5, nb = (hid >> 4) & 1, c16 = hid & 15;
    u8* base = whh8 + ((size_t)((d * 8 + w) * 4 + g)) * 8192;
    for (int k = tid; k < 256; k += 128) {
        int kc = k >> 5, q = (k >> 3) & 3, e = k & 7;
        base[(nb * 8 + kc) * 512 + (q * 16 + c16) * 8 + e] = f2fp8_manual(src[k]);
    }
}

// ============================================================
// Embedding + char conv + concat -> inp bf16 [16384][384]
// ============================================================
__global__ __launch_bounds__(128) void k_embed_conv(const int* __restrict__ words,
                                                    const int* __restrict__ chars,
                                                    const float* __restrict__ word_emb,
                                                    const float* __restrict__ char_emb,
                                                    const float* __restrict__ conv_w,
                                                    const float* __restrict__ conv_b,
                                                    u16* __restrict__ inp) {
    int pos = blockIdx.x, tid = threadIdx.x;
    __shared__ float ce[18 * 50];                      // rows 0 and 17 are zero pad
    const int* ch = chars + (size_t)pos * 16;
    for (int i = tid; i < 18 * 50; i += 128) {
        int row = i / 50, c = i - row * 50;
        float v = 0.f;
        if (row >= 1 && row <= 16) v = char_emb[(size_t)ch[row - 1] * 50 + c];
        ce[i] = v;
    }
    __syncthreads();
    {   // word embedding copy + zero pad
        const float* we = word_emb + (size_t)words[pos] * 300;
        u16* op = inp + (size_t)pos * KPAD;
        for (int c = tid; c < 300; c += 128) op[c] = f2bf(we[c]);
        for (int c = 350 + tid; c < KPAD; c += 128) op[c] = 0;
    }
    if (tid < 100) {
        int oc = tid >> 1, half = tid & 1, t0 = half * 8;
        float acc[8];
#pragma unroll
        for (int tt = 0; tt < 8; ++tt) acc[tt] = 0.f;
        const float* wrow = conv_w + (size_t)oc * 150;
        for (int ic = 0; ic < 50; ++ic) {
#pragma unroll
            for (int k = 0; k < 3; ++k) {
                float wv = wrow[ic * 3 + k];
#pragma unroll
                for (int tt = 0; tt < 8; ++tt)
                    acc[tt] = fmaf(ce[(t0 + tt + k) * 50 + ic], wv, acc[tt]);
            }
        }
        float cb = conv_b[oc];
        float m = 0.f;                                  // relu floor
#pragma unroll
        for (int tt = 0; tt < 8; ++tt) m = fmaxf(m, acc[tt] + cb);
        m = fmaxf(m, __shfl_xor(m, 1));
        if (half == 0) inp[(size_t)pos * KPAD + 300 + oc] = f2bf(m);
    }
}

// ============================================================
// GEMM: inp[16384][384] @ wih[2048][384]^T (bf16 MFMA). Epilogue adds the
// LSTM bias (position-independent) and writes xg2 packed for k_lstm:
// slot = ((d*8+grp)*128 + tt)*16384 + (w*64 + q*16 + c16)*32 + (nb*4+reg)*4 + gate
// with bwd time axis pre-reversed (tt).
// ============================================================
__global__ __launch_bounds__(256, 2) void k_gemm(const u16* __restrict__ A,
                                                 const u16* __restrict__ Bm,
                                                 u16* __restrict__ C,
                                                 const int* __restrict__ lengths,
                                                 const float* __restrict__ bias_f,
                                                 const float* __restrict__ bias_b) {
    __shared__ u16 sa[128 * 64];
    __shared__ u16 sb[128 * 64];
    int tid = threadIdx.x;
    int n0 = blockIdx.x * 128, m0 = blockIdx.y * 128;
    int lane = tid & 63, wid = tid >> 6;
    int wr = wid >> 1, wc = wid & 1;
    f32x4 acc[4][4];
#pragma unroll
    for (int mt = 0; mt < 4; ++mt)
#pragma unroll
        for (int nt = 0; nt < 4; ++nt) acc[mt][nt] = (f32x4){0.f, 0.f, 0.f, 0.f};

    for (int kt = 0; kt < 6; ++kt) {
#pragma unroll
        for (int c = 0; c < 4; ++c) {
            int idx = (c * 256 + tid) * 16;            // byte within 16KB tile
            int row = idx >> 7, colb = idx & 127;
            int dst = idx ^ ((row & 7) << 4);
            uint4 va = *(const uint4*)((const char*)A + (size_t)(m0 + row) * 768 + kt * 128 + colb);
            *(uint4*)((char*)sa + dst) = va;
            uint4 vb = *(const uint4*)((const char*)Bm + (size_t)(n0 + row) * 768 + kt * 128 + colb);
            *(uint4*)((char*)sb + dst) = vb;
        }
        __syncthreads();
#pragma unroll
        for (int kc = 0; kc < 2; ++kc) {
            bf16x8 af[4], bf[4];
#pragma unroll
            for (int mt = 0; mt < 4; ++mt) {
                int row = wr * 64 + mt * 16 + (lane & 15);
                int off = (row * 128 + kc * 64 + (lane >> 4) * 16) ^ ((row & 7) << 4);
                af[mt] = *(const bf16x8*)((const char*)sa + off);
            }
#pragma unroll
            for (int nt = 0; nt < 4; ++nt) {
                int row = wc * 64 + nt * 16 + (lane & 15);
                int off = (row * 128 + kc * 64 + (lane >> 4) * 16) ^ ((row & 7) << 4);
                bf[nt] = *(const bf16x8*)((const char*)sb + off);
            }
#pragma unroll
            for (int mt = 0; mt < 4; ++mt)
#pragma unroll
                for (int nt = 0; nt < 4; ++nt)
                    acc[mt][nt] = __builtin_amdgcn_mfma_f32_16x16x32_bf16(af[mt], bf[nt], acc[mt][nt], 0, 0, 0);
        }
        __syncthreads();
    }
    // epilogue: tile spans exactly batch element b = blockIdx.y (t = 0..127)
    int b = blockIdx.y;
    int len = lengths[b];
    int grp = b >> 4, row16 = b & 15;
    int qq = row16 >> 2, rg = row16 & 3;
    float bv[4];
    int dds[4], loffs[4];
#pragma unroll
    for (int nt = 0; nt < 4; ++nt) {
        int col = n0 + wc * 64 + nt * 16 + (lane & 15);
        int dd = col >> 10, rem = col & 1023;
        bv[nt] = (dd ? bias_b : bias_f)[rem];
        int gate = rem >> 8, hid = rem & 255;
        int w2 = hid >> 5, nb = (hid >> 4) & 1, cc = hid & 15;
        dds[nt] = dd;
        loffs[nt] = (w2 * 64 + qq * 16 + cc) * 32 + (nb * 4 + rg) * 4 + gate;
    }
#pragma unroll
    for (int mt = 0; mt < 4; ++mt)
#pragma unroll
        for (int nt = 0; nt < 4; ++nt) {
#pragma unroll
            for (int r = 0; r < 4; ++r) {
                int t = wr * 64 + mt * 16 + (lane >> 4) * 4 + r;
                int tt = dds[nt] ? ((t < len) ? (len - 1 - t) : t) : t;
                size_t slot = ((size_t)(dds[nt] * 8 + grp) * 128 + tt) * 16384 + loffs[nt];
                C[slot] = f2bf(acc[mt][nt][r] + bv[nt]);
            }
        }
}

// ============================================================
// BiLSTM recurrence, zero cross-WG sync, single barrier per step.
// 16 WGs = dir(2) x group(8, 16 batch rows). 512 threads = 8 waves; wave w owns
// hid block [32w, 32w+32). All 4 gates' w_hh register-resident as fp8
// (u64 br[4][16] = 128 VGPRs). h fp8 in double-buffered LDS (2x4KB, swizzled)
// so MFMA(t) and epilogue(t) of different waves overlap (one barrier/step).
// MFMA: v_mfma_f32_16x16x32_fp8_fp8 (M=16 rows, N=16 hid, K=32).
// ============================================================
__global__ __launch_bounds__(512, 2) void k_lstm(const u16* __restrict__ xg2,
                                                 const u8* __restrict__ whh8,
                                                 const int* __restrict__ lengths,
                                                 u16* __restrict__ hs) {
    __shared__ u8 h8[2][4096];                         // [buf][16 rows][256 hid], byte: r*256 + (k ^ ((r&7)<<3))
    int tid = threadIdx.x, lane = tid & 63, w = tid >> 6;
    int bx = blockIdx.x;
    int d = bx >> 3, grp = bx & 7;
    int c16 = lane & 15, q = lane >> 4;

    ((u64*)h8)[tid] = 0;                               // zero both buffers (1024 u64)
    ((u64*)h8)[tid + 512] = 0;

    int lenr[4];
#pragma unroll
    for (int rg = 0; rg < 4; ++rg) lenr[rg] = lengths[grp * 16 + q * 4 + rg];

    // register-resident fp8 weights: 4 gates x 16 (nb*8+kc) u64 frags = 128 VGPRs
    const u8* wbse = whh8 + ((size_t)((d * 8 + w) * 4)) * 8192;
    u64 br[4][16];
#pragma unroll
    for (int g = 0; g < 4; ++g)
#pragma unroll
        for (int j = 0; j < 16; ++j)
            br[g][j] = *(const u64*)(wbse + (size_t)g * 8192 + j * 512 + lane * 8);

    float cst[8];
    u8 hq[8];                                          // current h as fp8 (carried for masked rows)
#pragma unroll
    for (int u = 0; u < 8; ++u) { cst[u] = 0.f; hq[u] = 0; }

    // xg prefetch: 64B/lane = 4 uint4 = [unit(8)][gate(4)] u16 (bias pre-folded)
    const u16* xslab = xg2 + ((size_t)(d * 8 + grp) * 128) * 16384 + (w * 64 + lane) * 32;
    uint4 xq[4];
#pragma unroll
    for (int i = 0; i < 4; ++i) xq[i] = *(const uint4*)(xslab + i * 8);

    // A-frag LDS addressing (row r = c16, k = kc*32 + q*8 + e)
    int abase = c16 * 256, aswz = (c16 & 7) << 3, akoff = q * 8;

    __syncthreads();

    for (int t = 0; t < 128; ++t) {
        const u8* hcur = h8[t & 1];
        u8* hnxt = h8[(t + 1) & 1];

        f32x4 acc[8];
#pragma unroll
        for (int u = 0; u < 8; ++u) acc[u] = (f32x4){0.f, 0.f, 0.f, 0.f};

#pragma unroll
        for (int kc = 0; kc < 8; ++kc) {
            long long a = *(const long long*)(hcur + abase + ((kc * 32 + akoff) ^ aswz));
#pragma unroll
            for (int nb = 0; nb < 2; ++nb)
#pragma unroll
                for (int g = 0; g < 4; ++g)
                    acc[nb * 4 + g] = __builtin_amdgcn_mfma_f32_16x16x32_fp8_fp8(
                        a, (long long)br[g][nb * 8 + kc], acc[nb * 4 + g], 0, 0, 0);
        }

        // unpack xq into u32 words (static indices), then prefetch next step
        u32 xw[16];
#pragma unroll
        for (int i = 0; i < 4; ++i) {
            xw[i * 4 + 0] = xq[i].x; xw[i * 4 + 1] = xq[i].y;
            xw[i * 4 + 2] = xq[i].z; xw[i * 4 + 3] = xq[i].w;
        }
        if (t < 127) {
            const u16* xb = xslab + (size_t)(t + 1) * 16384;
#pragma unroll
            for (int i = 0; i < 4; ++i) xq[i] = *(const uint4*)(xb + i * 8);
        }

#pragma unroll
        for (int nb = 0; nb < 2; ++nb)
#pragma unroll
            for (int rg = 0; rg < 4; ++rg) {
                int u = nb * 4 + rg;
                float pi = acc[nb * 4 + 0][rg] + bf2f((u16)(xw[u * 2] & 0xffff));
                float pf = acc[nb * 4 + 1][rg] + bf2f((u16)(xw[u * 2] >> 16));
                float pg = acc[nb * 4 + 2][rg] + bf2f((u16)(xw[u * 2 + 1] & 0xffff));
                float po = acc[nb * 4 + 3][rg] + bf2f((u16)(xw[u * 2 + 1] >> 16));
                float gi = sigm(pi);
                float gf = sigm(pf);
                float gg = tanh_(pg);
                float go = sigm(po);
                float cn = gf * cst[u] + gi * gg;
                float hn = go * tanh_(cn);
                int len = lenr[rg];
                int row = q * 4 + rg;
                int hid = w * 32 + nb * 16 + c16;
                if (t < len) {
                    cst[u] = cn;
                    hq[u] = f2fp8(hn);
                    int pout = d ? (len - 1 - t) : t;
                    hs[((size_t)((grp * 16 + row) * 128 + pout)) * 512 + d * 256 + hid] = f2bf(hn);
                }
                hnxt[row * 256 + (hid ^ ((row & 7) << 3))] = hq[u];   // carry for masked rows too
            }
        __syncthreads();
    }
}

// ============================================================
// Emissions: emis[pos][17] = hs[pos][512] . proj_w[17][512] + proj_b
// ============================================================
__global__ __launch_bounds__(256) void k_emis(const u16* __restrict__ hs,
                                              const float* __restrict__ proj_w,
                                              const float* __restrict__ proj_b,
                                              float* __restrict__ emis) {
    __shared__ float pw[17 * 512];
    int tid = threadIdx.x;
    for (int i = tid; i < 17 * 512; i += 256) pw[i] = proj_w[i];
    __syncthreads();
    int lane = tid & 63, wv = tid >> 6;
    int pos = blockIdx.x * 4 + wv;
    float hv[8];
    const u16* hp = hs + (size_t)pos * 512 + lane * 8;
#pragma unroll
    for (int j = 0; j < 8; ++j) hv[j] = bf2f(hp[j]);
    for (int tg = 0; tg < 17; ++tg) {
        const float* wp = pw + tg * 512 + lane * 8;
        float s = 0.f;
#pragma unroll
        for (int j = 0; j < 8; ++j) s = fmaf(hv[j], wp[j], s);
#pragma unroll
        for (int off = 32; off; off >>= 1) s += __shfl_down(s, off);
        if (lane == 0) emis[(size_t)pos * 17 + tg] = s + proj_b[tg];
    }
}

// ============================================================
// CRF per-sample NLL. One 64-thread block per batch element.
// ============================================================
__global__ __launch_bounds__(64) void k_crf(const float* __restrict__ emis,
                                            const int* __restrict__ tags,
                                            const int* __restrict__ lengths,
                                            const float* __restrict__ trans,
                                            const float* __restrict__ start_trans,
                                            const float* __restrict__ end_trans,
                                            float* __restrict__ nll) {
    int b = blockIdx.x, lane = threadIdx.x;
    __shared__ float tr[289];
    __shared__ float al[17];
    __shared__ float scs;
    for (int i = lane; i < 289; i += 64) tr[i] = trans[i];
    int len = lengths[b];
    const int* tg = tags + (size_t)b * 128;
    const float* em = emis + (size_t)b * 128 * 17;
    __syncthreads();

    float sc = 0.f;
    for (int t = lane; t < len; t += 64) {
        sc += em[t * 17 + tg[t]];
        if (t >= 1) sc += tr[tg[t - 1] * 17 + tg[t]];
    }
#pragma unroll
    for (int off = 32; off; off >>= 1) sc += __shfl_down(sc, off);
    if (lane == 0) scs = sc + start_trans[tg[0]] + end_trans[tg[len - 1]];

    if (lane < 17) al[lane] = start_trans[lane] + em[lane];
    __syncthreads();
    for (int t = 1; t < len; ++t) {
        float anew = 0.f;
        if (lane < 17) {
            float m = -1e30f;
            for (int i = 0; i < 17; ++i) m = fmaxf(m, al[i] + tr[i * 17 + lane]);
            float s = 0.f;
            for (int i = 0; i < 17; ++i) s += __expf(al[i] + tr[i * 17 + lane] - m);
            anew = m + __logf(s) + em[t * 17 + lane];
        }
        __syncthreads();
        if (lane < 17) al[lane] = anew;
        __syncthreads();
    }
    float v = (lane < 17) ? al[lane] + end_trans[lane] : -1e30f;
    float m = v;
#pragma unroll
    for (int off = 32; off; off >>= 1) m = fmaxf(m, __shfl_xor(m, off));
    float s = (lane < 17) ? __expf(v - m) : 0.f;
#pragma unroll
    for (int off = 32; off; off >>= 1) s += __shfl_xor(s, off);
    if (lane == 0) nll[b] = (m + __logf(s)) - scs;
}

__global__ __launch_bounds__(128) void k_reduce(const float* __restrict__ nll, float* __restrict__ out) {
    int tid = threadIdx.x;
    float v = nll[tid];
#pragma unroll
    for (int off = 32; off; off >>= 1) v += __shfl_down(v, off);
    __shared__ float partial[2];
    if ((tid & 63) == 0) partial[tid >> 6] = v;
    __syncthreads();
    if (tid == 0) out[0] = partial[0] + partial[1];
}

// ============================================================
extern "C" void kernel_launch(void* const* d_in, const int* in_sizes, int n_in,
                              void* d_out, int out_size, void* d_ws, size_t ws_size,
                              hipStream_t stream) {
    (void)in_sizes; (void)n_in; (void)out_size; (void)ws_size;
    const int*   words       = (const int*)d_in[0];
    const int*   chars       = (const int*)d_in[1];
    const int*   tags        = (const int*)d_in[2];
    const int*   lengths     = (const int*)d_in[3];
    const float* word_emb    = (const float*)d_in[4];
    const float* char_emb    = (const float*)d_in[5];
    const float* conv_w      = (const float*)d_in[6];
    const float* conv_b      = (const float*)d_in[7];
    const float* w_ih_f      = (const float*)d_in[8];
    const float* w_hh_f      = (const float*)d_in[9];
    const float* b_f         = (const float*)d_in[10];
    const float* w_ih_b      = (const float*)d_in[11];
    const float* w_hh_b      = (const float*)d_in[12];
    const float* b_b         = (const float*)d_in[13];
    const float* proj_w      = (const float*)d_in[14];
    const float* proj_b      = (const float*)d_in[15];
    const float* trans       = (const float*)d_in[16];
    const float* start_trans = (const float*)d_in[17];
    const float* end_trans   = (const float*)d_in[18];

    char* ws = (char*)d_ws;
    u16* inp   = (u16*)(ws + OFF_INP);
    u16* wih   = (u16*)(ws + OFF_WIH);
    u8*  whh8  = (u8*)(ws + OFF_WHH);
    u16* xgb   = (u16*)(ws + OFF_XG);
    u16* hsb   = (u16*)(ws + OFF_HS);
    float* em  = (float*)(ws + OFF_EMIS);
    float* nll = (float*)(ws + OFF_NLL);

    k_prep_wih<<<2048, 128, 0, stream>>>(w_ih_f, w_ih_b, wih);
    k_prep_whh8<<<2048, 128, 0, stream>>>(w_hh_f, w_hh_b, whh8);
    k_embed_conv<<<NPOS, 128, 0, stream>>>(words, chars, word_emb, char_emb, conv_w, conv_b, inp);
    k_gemm<<<dim3(16, 128), 256, 0, stream>>>(inp, wih, xgb, lengths, b_f, b_b);
    k_lstm<<<16, 512, 0, stream>>>(xgb, whh8, lengths, hsb);
    k_emis<<<4096, 256, 0, stream>>>(hsb, proj_w, proj_b, em);
    k_crf<<<128, 64, 0, stream>>>(em, tags, lengths, trans, start_trans, end_trans, nll);
    k_reduce<<<1, 128, 0, stream>>>(nll, (float*)d_out);
}

// Round 6
// 722.731 us; speedup vs baseline: 2.3680x; 1.1783x over previous
//
#include <hip/hip_runtime.h>
#include <stdint.h>

typedef unsigned char u8;
typedef unsigned short u16;
typedef unsigned int u32;
typedef unsigned long long u64;

// ---- problem constants ----
// B=128 S=128 WL=16 V=50000 C=100 T=17 WE=300 CE=50 CF=50 K=3 H=256 D=350
#define NPOS 16384          // B*S
#define KPAD 384            // D padded to multiple of 64

typedef __attribute__((ext_vector_type(8))) short bf16x8;
typedef __attribute__((ext_vector_type(4))) float f32x4;

__device__ __forceinline__ float bf2f(u16 u) { return __uint_as_float(((u32)u) << 16); }
__device__ __forceinline__ u16 f2bf(float f) {
    u32 u = __float_as_uint(f);
    u += 0x7fffu + ((u >> 16) & 1u);   // RNE
    return (u16)(u >> 16);
}
__device__ __forceinline__ float frcp(float x) {
#if __has_builtin(__builtin_amdgcn_rcpf)
    return __builtin_amdgcn_rcpf(x);       // v_rcp_f32, 1ulp — fine vs fp8 weights
#else
    return 1.0f / x;
#endif
}
__device__ __forceinline__ float sigm(float x) { return frcp(1.0f + __expf(-x)); }
__device__ __forceinline__ float tanh_(float x) { return fmaf(2.0f, frcp(1.0f + __expf(-2.0f * x)), -1.0f); }

// f32 -> fp8 e4m3fn (OCP), RNE, clamp to +-448. Prep-path (manual, no builtin risk).
__device__ u8 f2fp8_manual(float f) {
    u32 u = __float_as_uint(f);
    u32 s = (u >> 31) << 7;
    u32 ae = (u >> 23) & 255u;
    u32 m = u & 0x7fffffu;
    int e = (int)ae - 127;
    if (ae == 0) return (u8)s;                 // f32 subnormal -> 0
    if (e >= 9) return (u8)(s | 0x7e);         // >= 512 -> clamp 448
    if (e >= -6) {                             // e4m3 normal
        u32 mant = m >> 20;
        u32 rem = m & 0xfffffu;
        if (rem > 0x80000u || (rem == 0x80000u && (mant & 1u))) mant++;
        u32 ef = (u32)(e + 7);
        if (mant == 8u) { mant = 0u; ef++; }
        if (ef >= 16u || (ef == 15u && mant == 7u)) return (u8)(s | 0x7e);
        return (u8)(s | (ef << 3) | mant);
    }
    if (e < -10) return (u8)s;                 // underflow to 0
    int sb = 14 - e;                           // shift for units of 2^-9
    u32 X = 0x800000u | m;
    u32 mant = X >> sb;
    u32 rem = X & ((1u << sb) - 1u);
    u32 half = 1u << (sb - 1);
    if (rem > half || (rem == half && (mant & 1u))) mant++;
    if (mant >= 8u) return (u8)(s | (1u << 3)); // rounds to first normal 2^-6
    return (u8)(s | mant);
}

__device__ __forceinline__ u8 f2fp8(float f) {
#if __has_builtin(__builtin_amdgcn_cvt_pk_fp8_f32)
    return (u8)(__builtin_amdgcn_cvt_pk_fp8_f32(f, f, 0, false) & 0xff);
#else
    return f2fp8_manual(f);
#endif
}

// ---- workspace layout (bytes) ----
static constexpr size_t OFF_INP  = 0;                       // u16 [16384][384]   = 12582912
static constexpr size_t OFF_WIH  = 12582912;                // u16 [2048][384]    = 1572864
static constexpr size_t OFF_WHH  = 14155776;                // fp8 packed 512KB
static constexpr size_t OFF_XG   = 15204352;                // u16 xg2 repacked   = 67108864
static constexpr size_t OFF_HS   = 82313216;                // u16 [16384][512]   = 16777216
static constexpr size_t OFF_EMIS = 99090432;                // f32 [16384][17]    = 1114112
static constexpr size_t OFF_NLL  = 100204544;               // f32 [128]

// ============================================================
// Prep: pack [w_ih_f; w_ih_b] into bf16 [2048][384] (K padded w/ zeros)
// ============================================================
__global__ __launch_bounds__(128) void k_prep_wih(const float* __restrict__ wf,
                                                  const float* __restrict__ wb,
                                                  u16* __restrict__ wih) {
    int n = blockIdx.x, tid = threadIdx.x;
    const float* src = (n < 1024) ? (wf + (size_t)n * 350) : (wb + (size_t)(n - 1024) * 350);
    u16* dst = wih + (size_t)n * KPAD;
    for (int k = tid; k < KPAD; k += 128) dst[k] = (k < 350) ? f2bf(src[k]) : (u16)0;
}

// ============================================================
// Prep: w_hh (both dirs) -> fp8, packed for 16x16x32 B-frags:
// whh8[((d*8+w)*4+g)*8192 + (nb*8+kc)*512 + (q*16+c16)*8 + e]
// where hid = w*32+nb*16+c16, k = kc*32 + q*8 + e
// ============================================================
__global__ __launch_bounds__(128) void k_prep_whh8(const float* __restrict__ wf,
                                                   const float* __restrict__ wb,
                                                   u8* __restrict__ whh8) {
    int bx = blockIdx.x, tid = threadIdx.x;
    int d = bx >> 10, row = bx & 1023;                 // row = gate*256 + hid
    const float* src = (d ? wb : wf) + (size_t)row * 256;
    int g = row >> 8, hid = row & 255;
    int w = hid >> 5, nb = (hid >> 4) & 1, c16 = hid & 15;
    u8* base = whh8 + ((size_t)((d * 8 + w) * 4 + g)) * 8192;
    for (int k = tid; k < 256; k += 128) {
        int kc = k >> 5, q = (k >> 3) & 3, e = k & 7;
        base[(nb * 8 + kc) * 512 + (q * 16 + c16) * 8 + e] = f2fp8_manual(src[k]);
    }
}

// ============================================================
// Embedding + char conv + concat -> inp bf16 [16384][384]
// ============================================================
__global__ __launch_bounds__(128) void k_embed_conv(const int* __restrict__ words,
                                                    const int* __restrict__ chars,
                                                    const float* __restrict__ word_emb,
                                                    const float* __restrict__ char_emb,
                                                    const float* __restrict__ conv_w,
                                                    const float* __restrict__ conv_b,
                                                    u16* __restrict__ inp) {
    int pos = blockIdx.x, tid = threadIdx.x;
    __shared__ float ce[18 * 50];                      // rows 0 and 17 are zero pad
    const int* ch = chars + (size_t)pos * 16;
    for (int i = tid; i < 18 * 50; i += 128) {
        int row = i / 50, c = i - row * 50;
        float v = 0.f;
        if (row >= 1 && row <= 16) v = char_emb[(size_t)ch[row - 1] * 50 + c];
        ce[i] = v;
    }
    __syncthreads();
    {   // word embedding copy + zero pad
        const float* we = word_emb + (size_t)words[pos] * 300;
        u16* op = inp + (size_t)pos * KPAD;
        for (int c = tid; c < 300; c += 128) op[c] = f2bf(we[c]);
        for (int c = 350 + tid; c < KPAD; c += 128) op[c] = 0;
    }
    if (tid < 100) {
        int oc = tid >> 1, half = tid & 1, t0 = half * 8;
        float acc[8];
#pragma unroll
        for (int tt = 0; tt < 8; ++tt) acc[tt] = 0.f;
        const float* wrow = conv_w + (size_t)oc * 150;
        for (int ic = 0; ic < 50; ++ic) {
#pragma unroll
            for (int k = 0; k < 3; ++k) {
                float wv = wrow[ic * 3 + k];
#pragma unroll
                for (int tt = 0; tt < 8; ++tt)
                    acc[tt] = fmaf(ce[(t0 + tt + k) * 50 + ic], wv, acc[tt]);
            }
        }
        float cb = conv_b[oc];
        float m = 0.f;                                  // relu floor
#pragma unroll
        for (int tt = 0; tt < 8; ++tt) m = fmaxf(m, acc[tt] + cb);
        m = fmaxf(m, __shfl_xor(m, 1));
        if (half == 0) inp[(size_t)pos * KPAD + 300 + oc] = f2bf(m);
    }
}

// ============================================================
// GEMM: inp[16384][384] @ wih[2048][384]^T (bf16 MFMA). Epilogue adds the
// LSTM bias (position-independent) and writes xg2 packed for k_lstm:
// slot = ((d*8+grp)*128 + tt)*16384 + (w*64 + q*16 + c16)*32 + (nb*4+reg)*4 + gate
// with bwd time axis pre-reversed (tt).
// ============================================================
__global__ __launch_bounds__(256, 2) void k_gemm(const u16* __restrict__ A,
                                                 const u16* __restrict__ Bm,
                                                 u16* __restrict__ C,
                                                 const int* __restrict__ lengths,
                                                 const float* __restrict__ bias_f,
                                                 const float* __restrict__ bias_b) {
    __shared__ u16 sa[128 * 64];
    __shared__ u16 sb[128 * 64];
    int tid = threadIdx.x;
    int n0 = blockIdx.x * 128, m0 = blockIdx.y * 128;
    int lane = tid & 63, wid = tid >> 6;
    int wr = wid >> 1, wc = wid & 1;
    f32x4 acc[4][4];
#pragma unroll
    for (int mt = 0; mt < 4; ++mt)
#pragma unroll
        for (int nt = 0; nt < 4; ++nt) acc[mt][nt] = (f32x4){0.f, 0.f, 0.f, 0.f};

    for (int kt = 0; kt < 6; ++kt) {
#pragma unroll
        for (int c = 0; c < 4; ++c) {
            int idx = (c * 256 + tid) * 16;            // byte within 16KB tile
            int row = idx >> 7, colb = idx & 127;
            int dst = idx ^ ((row & 7) << 4);
            uint4 va = *(const uint4*)((const char*)A + (size_t)(m0 + row) * 768 + kt * 128 + colb);
            *(uint4*)((char*)sa + dst) = va;
            uint4 vb = *(const uint4*)((const char*)Bm + (size_t)(n0 + row) * 768 + kt * 128 + colb);
            *(uint4*)((char*)sb + dst) = vb;
        }
        __syncthreads();
#pragma unroll
        for (int kc = 0; kc < 2; ++kc) {
            bf16x8 af[4], bf[4];
#pragma unroll
            for (int mt = 0; mt < 4; ++mt) {
                int row = wr * 64 + mt * 16 + (lane & 15);
                int off = (row * 128 + kc * 64 + (lane >> 4) * 16) ^ ((row & 7) << 4);
                af[mt] = *(const bf16x8*)((const char*)sa + off);
            }
#pragma unroll
            for (int nt = 0; nt < 4; ++nt) {
                int row = wc * 64 + nt * 16 + (lane & 15);
                int off = (row * 128 + kc * 64 + (lane >> 4) * 16) ^ ((row & 7) << 4);
                bf[nt] = *(const bf16x8*)((const char*)sb + off);
            }
#pragma unroll
            for (int mt = 0; mt < 4; ++mt)
#pragma unroll
                for (int nt = 0; nt < 4; ++nt)
                    acc[mt][nt] = __builtin_amdgcn_mfma_f32_16x16x32_bf16(af[mt], bf[nt], acc[mt][nt], 0, 0, 0);
        }
        __syncthreads();
    }
    // epilogue: tile spans exactly batch element b = blockIdx.y (t = 0..127)
    int b = blockIdx.y;
    int len = lengths[b];
    int grp = b >> 4, row16 = b & 15;
    int qq = row16 >> 2, rg = row16 & 3;
    float bv[4];
    int dds[4], loffs[4];
#pragma unroll
    for (int nt = 0; nt < 4; ++nt) {
        int col = n0 + wc * 64 + nt * 16 + (lane & 15);
        int dd = col >> 10, rem = col & 1023;
        bv[nt] = (dd ? bias_b : bias_f)[rem];
        int gate = rem >> 8, hid = rem & 255;
        int w2 = hid >> 5, nb = (hid >> 4) & 1, cc = hid & 15;
        dds[nt] = dd;
        loffs[nt] = (w2 * 64 + qq * 16 + cc) * 32 + (nb * 4 + rg) * 4 + gate;
    }
#pragma unroll
    for (int mt = 0; mt < 4; ++mt)
#pragma unroll
        for (int nt = 0; nt < 4; ++nt) {
#pragma unroll
            for (int r = 0; r < 4; ++r) {
                int t = wr * 64 + mt * 16 + (lane >> 4) * 4 + r;
                int tt = dds[nt] ? ((t < len) ? (len - 1 - t) : t) : t;
                size_t slot = ((size_t)(dds[nt] * 8 + grp) * 128 + tt) * 16384 + loffs[nt];
                C[slot] = f2bf(acc[mt][nt][r] + bv[nt]);
            }
        }
}

// ============================================================
// BiLSTM recurrence. 16 WGs = dir(2) x group(8, 16 rows). 512 thr = 8 waves.
// All 4 gates register-resident fp8 (u64 br[4][16]). h fp8 double-buffered LDS.
// R6: rcp-based gate math (no IEEE div), xg prefetch issued at step START via
// double-buffered register sets (macro-unrolled 2 steps), hoisted addresses.
// ============================================================
#define LSTM_STEP(T, XC, XN, HC, HN)                                              \
    {                                                                             \
        if ((T) < 127) {                                                          \
            const u16* xb_ = xslab + (size_t)((T) + 1) * 16384;                   \
            *(uint4*)(&XN[0])  = *(const uint4*)(xb_);                            \
            *(uint4*)(&XN[4])  = *(const uint4*)(xb_ + 8);                        \
            *(uint4*)(&XN[8])  = *(const uint4*)(xb_ + 16);                       \
            *(uint4*)(&XN[12]) = *(const uint4*)(xb_ + 24);                       \
        }                                                                         \
        f32x4 acc[8];                                                             \
        _Pragma("unroll") for (int u = 0; u < 8; ++u)                             \
            acc[u] = (f32x4){0.f, 0.f, 0.f, 0.f};                                 \
        _Pragma("unroll") for (int kc = 0; kc < 8; ++kc) {                        \
            long long a = *(const long long*)((HC) + abase + ((kc * 32 + akoff) ^ aswz)); \
            _Pragma("unroll") for (int nb = 0; nb < 2; ++nb)                      \
                _Pragma("unroll") for (int g = 0; g < 4; ++g)                     \
                    acc[nb * 4 + g] = __builtin_amdgcn_mfma_f32_16x16x32_fp8_fp8( \
                        a, (long long)br[g][nb * 8 + kc], acc[nb * 4 + g], 0, 0, 0); \
        }                                                                         \
        int toff_ = (T) * dstep;                                                  \
        _Pragma("unroll") for (int nb = 0; nb < 2; ++nb)                          \
            _Pragma("unroll") for (int rg = 0; rg < 4; ++rg) {                    \
                int u = nb * 4 + rg;                                              \
                float pi = acc[nb * 4 + 0][rg] + bf2f((u16)(XC[u * 2] & 0xffff)); \
                float pf = acc[nb * 4 + 1][rg] + bf2f((u16)(XC[u * 2] >> 16));    \
                float pg = acc[nb * 4 + 2][rg] + bf2f((u16)(XC[u * 2 + 1] & 0xffff)); \
                float po = acc[nb * 4 + 3][rg] + bf2f((u16)(XC[u * 2 + 1] >> 16)); \
                float gi = sigm(pi), gf = sigm(pf), gg = tanh_(pg), go = sigm(po); \
                float cn = gf * cst[u] + gi * gg;                                 \
                float hn = go * tanh_(cn);                                        \
                if ((T) < lenr[rg]) {                                             \
                    cst[u] = cn;                                                  \
                    hq[u] = f2fp8(hn);                                            \
                    hs[hsb[u] + toff_] = f2bf(hn);                                \
                }                                                                 \
                (HN)[hrow[u]] = hq[u];                                            \
            }                                                                     \
        __syncthreads();                                                          \
    }

__global__ __launch_bounds__(512, 2) void k_lstm(const u16* __restrict__ xg2,
                                                 const u8* __restrict__ whh8,
                                                 const int* __restrict__ lengths,
                                                 u16* __restrict__ hs) {
    __shared__ u8 h8[2][4096];                         // [buf][16 rows][256 hid], byte: r*256 + (k ^ ((r&7)<<3))
    int tid = threadIdx.x, lane = tid & 63, w = tid >> 6;
    int bx = blockIdx.x;
    int d = bx >> 3, grp = bx & 7;
    int c16 = lane & 15, q = lane >> 4;

    ((u64*)h8)[tid] = 0;                               // zero both buffers (1024 u64)
    ((u64*)h8)[tid + 512] = 0;

    int lenr[4];
#pragma unroll
    for (int rg = 0; rg < 4; ++rg) lenr[rg] = lengths[grp * 16 + q * 4 + rg];

    // register-resident fp8 weights: 4 gates x 16 (nb*8+kc) u64 frags = 128 VGPRs
    const u8* wbse = whh8 + ((size_t)((d * 8 + w) * 4)) * 8192;
    u64 br[4][16];
#pragma unroll
    for (int g = 0; g < 4; ++g)
#pragma unroll
        for (int j = 0; j < 16; ++j)
            br[g][j] = *(const u64*)(wbse + (size_t)g * 8192 + j * 512 + lane * 8);

    float cst[8];
    u8 hq[8];                                          // current h as fp8 (carried for masked rows)
#pragma unroll
    for (int u = 0; u < 8; ++u) { cst[u] = 0.f; hq[u] = 0; }

    // hoisted per-unit addresses
    u32 hrow[8];                                       // LDS write offsets
    u32 hsb[8];                                        // hs elem base (t=0 / t=len-1)
    int dstep = d ? -512 : 512;
#pragma unroll
    for (int nb = 0; nb < 2; ++nb)
#pragma unroll
        for (int rg = 0; rg < 4; ++rg) {
            int u = nb * 4 + rg;
            int row = q * 4 + rg;
            int hid = w * 32 + nb * 16 + c16;
            hrow[u] = row * 256 + (hid ^ ((row & 7) << 3));
            int p0 = d ? (lenr[rg] - 1) : 0;
            hsb[u] = ((u32)((grp * 16 + row) * 128 + p0)) * 512 + d * 256 + hid;
        }

    // xg: bias pre-folded; 64B/lane/step
    const u16* xslab = xg2 + ((size_t)(d * 8 + grp) * 128) * 16384 + (w * 64 + lane) * 32;
    u32 xqa[16], xqb[16];
    *(uint4*)(&xqa[0])  = *(const uint4*)(xslab);
    *(uint4*)(&xqa[4])  = *(const uint4*)(xslab + 8);
    *(uint4*)(&xqa[8])  = *(const uint4*)(xslab + 16);
    *(uint4*)(&xqa[12]) = *(const uint4*)(xslab + 24);

    // A-frag LDS addressing (row r = c16, k = kc*32 + q*8 + e)
    int abase = c16 * 256, aswz = (c16 & 7) << 3, akoff = q * 8;

    __syncthreads();

    for (int t2 = 0; t2 < 128; t2 += 2) {
        LSTM_STEP(t2,     xqa, xqb, h8[0], h8[1]);
        LSTM_STEP(t2 + 1, xqb, xqa, h8[1], h8[0]);
    }
}

// ============================================================
// Emissions: emis[pos][17] = hs[pos][512] . proj_w[17][512] + proj_b
// ============================================================
__global__ __launch_bounds__(256) void k_emis(const u16* __restrict__ hs,
                                              const float* __restrict__ proj_w,
                                              const float* __restrict__ proj_b,
                                              float* __restrict__ emis) {
    __shared__ float pw[17 * 512];
    int tid = threadIdx.x;
    for (int i = tid; i < 17 * 512; i += 256) pw[i] = proj_w[i];
    __syncthreads();
    int lane = tid & 63, wv = tid >> 6;
    int pos = blockIdx.x * 4 + wv;
    float hv[8];
    const u16* hp = hs + (size_t)pos * 512 + lane * 8;
#pragma unroll
    for (int j = 0; j < 8; ++j) hv[j] = bf2f(hp[j]);
    for (int tg = 0; tg < 17; ++tg) {
        const float* wp = pw + tg * 512 + lane * 8;
        float s = 0.f;
#pragma unroll
        for (int j = 0; j < 8; ++j) s = fmaf(hv[j], wp[j], s);
#pragma unroll
        for (int off = 32; off; off >>= 1) s += __shfl_down(s, off);
        if (lane == 0) emis[(size_t)pos * 17 + tg] = s + proj_b[tg];
    }
}

// ============================================================
// CRF per-sample NLL. One 64-thread block per batch element.
// ============================================================
__global__ __launch_bounds__(64) void k_crf(const float* __restrict__ emis,
                                            const int* __restrict__ tags,
                                            const int* __restrict__ lengths,
                                            const float* __restrict__ trans,
                                            const float* __restrict__ start_trans,
                                            const float* __restrict__ end_trans,
                                            float* __restrict__ nll) {
    int b = blockIdx.x, lane = threadIdx.x;
    __shared__ float tr[289];
    __shared__ float al[17];
    __shared__ float scs;
    for (int i = lane; i < 289; i += 64) tr[i] = trans[i];
    int len = lengths[b];
    const int* tg = tags + (size_t)b * 128;
    const float* em = emis + (size_t)b * 128 * 17;
    __syncthreads();

    float sc = 0.f;
    for (int t = lane; t < len; t += 64) {
        sc += em[t * 17 + tg[t]];
        if (t >= 1) sc += tr[tg[t - 1] * 17 + tg[t]];
    }
#pragma unroll
    for (int off = 32; off; off >>= 1) sc += __shfl_down(sc, off);
    if (lane == 0) scs = sc + start_trans[tg[0]] + end_trans[tg[len - 1]];

    if (lane < 17) al[lane] = start_trans[lane] + em[lane];
    __syncthreads();
    for (int t = 1; t < len; ++t) {
        float anew = 0.f;
        if (lane < 17) {
            float m = -1e30f;
            for (int i = 0; i < 17; ++i) m = fmaxf(m, al[i] + tr[i * 17 + lane]);
            float s = 0.f;
            for (int i = 0; i < 17; ++i) s += __expf(al[i] + tr[i * 17 + lane] - m);
            anew = m + __logf(s) + em[t * 17 + lane];
        }
        __syncthreads();
        if (lane < 17) al[lane] = anew;
        __syncthreads();
    }
    float v = (lane < 17) ? al[lane] + end_trans[lane] : -1e30f;
    float m = v;
#pragma unroll
    for (int off = 32; off; off >>= 1) m = fmaxf(m, __shfl_xor(m, off));
    float s = (lane < 17) ? __expf(v - m) : 0.f;
#pragma unroll
    for (int off = 32; off; off >>= 1) s += __shfl_xor(s, off);
    if (lane == 0) nll[b] = (m + __logf(s)) - scs;
}

__global__ __launch_bounds__(128) void k_reduce(const float* __restrict__ nll, float* __restrict__ out) {
    int tid = threadIdx.x;
    float v = nll[tid];
#pragma unroll
    for (int off = 32; off; off >>= 1) v += __shfl_down(v, off);
    __shared__ float partial[2];
    if ((tid & 63) == 0) partial[tid >> 6] = v;
    __syncthreads();
    if (tid == 0) out[0] = partial[0] + partial[1];
}

// ============================================================
extern "C" void kernel_launch(void* const* d_in, const int* in_sizes, int n_in,
                              void* d_out, int out_size, void* d_ws, size_t ws_size,
                              hipStream_t stream) {
    (void)in_sizes; (void)n_in; (void)out_size; (void)ws_size;
    const int*   words       = (const int*)d_in[0];
    const int*   chars       = (const int*)d_in[1];
    const int*   tags        = (const int*)d_in[2];
    const int*   lengths     = (const int*)d_in[3];
    const float* word_emb    = (const float*)d_in[4];
    const float* char_emb    = (const float*)d_in[5];
    const float* conv_w      = (const float*)d_in[6];
    const float* conv_b      = (const float*)d_in[7];
    const float* w_ih_f      = (const float*)d_in[8];
    const float* w_hh_f      = (const float*)d_in[9];
    const float* b_f         = (const float*)d_in[10];
    const float* w_ih_b      = (const float*)d_in[11];
    const float* w_hh_b      = (const float*)d_in[12];
    const float* b_b         = (const float*)d_in[13];
    const float* proj_w      = (const float*)d_in[14];
    const float* proj_b      = (const float*)d_in[15];
    const float* trans       = (const float*)d_in[16];
    const float* start_trans = (const float*)d_in[17];
    const float* end_trans   = (const float*)d_in[18];

    char* ws = (char*)d_ws;
    u16* inp   = (u16*)(ws + OFF_INP);
    u16* wih   = (u16*)(ws + OFF_WIH);
    u8*  whh8  = (u8*)(ws + OFF_WHH);
    u16* xgb   = (u16*)(ws + OFF_XG);
    u16* hsb   = (u16*)(ws + OFF_HS);
    float* em  = (float*)(ws + OFF_EMIS);
    float* nll = (float*)(ws + OFF_NLL);

    k_prep_wih<<<2048, 128, 0, stream>>>(w_ih_f, w_ih_b, wih);
    k_prep_whh8<<<2048, 128, 0, stream>>>(w_hh_f, w_hh_b, whh8);
    k_embed_conv<<<NPOS, 128, 0, stream>>>(words, chars, word_emb, char_emb, conv_w, conv_b, inp);
    k_gemm<<<dim3(16, 128), 256, 0, stream>>>(inp, wih, xgb, lengths, b_f, b_b);
    k_lstm<<<16, 512, 0, stream>>>(xgb, whh8, lengths, hsb);
    k_emis<<<4096, 256, 0, stream>>>(hsb, proj_w, proj_b, em);
    k_crf<<<128, 64, 0, stream>>>(em, tags, lengths, trans, start_trans, end_trans, nll);
    k_reduce<<<1, 128, 0, stream>>>(nll, (float*)d_out);
}